// Round 2
// baseline (177.547 us; speedup 1.0000x reference)
//
#include <hip/hip_runtime.h>

// BurstSnn: 32-step burst-encoder + 2-layer LIF SNN, B=16384, D=187, H=50, C=5.
// R10 = R9 (152.7us bench / 103us dispatch) restructured:
//  (1) TWO batch elements per wave: A in lanes 0-31, B in lanes 32-63.
//      One ballot yields both elements' 32-bit group masks (lo/hi halves);
//      encoder, LIF1, LIF2 and stores run ONCE for both elements -> fixed
//      per-element cost roughly halves. 1 step per iteration (no pairing).
//  (2) WAVE-UNIFORM GATHER SCAN: ballot masks live in SGPRs; scanning one
//      mask at a time moves ffbl/clear/offset bookkeeping to the free SALU
//      pipe (s_ff1/s_and/s_lshl overlap VALU). Per spike: 1 v_add (addr) +
//      1 v_pk_add_f32 + 1 ds_read with row-base folded into the offset:
//      immediate = 2 VALU/spike (was ~5.7), exact trip counts (no max-waste,
//      no zero rows).
// Arithmetic per element is instruction-identical to R9 (absmax 0.0): same
// encoder sequence, same 6 group accumulators merged ((((a0+a1)+a2)+a3)+a4)+a5,
// within-group ascending-d, L2 = (sum lo) + (sum hi) each ascending-h, same
// LIF order. Early exit now requires BOTH elements dead (checked every step).

constexpr int D = 187;
constexpr int H = 50;
constexpr int C = 5;
constexpr int T = 32;
constexpr int WPB = 16;          // waves per block
constexpr int EPB = WPB * 2;     // elements per block (2 per wave)
constexpr int ROWS1 = 193;       // rows rd = 33*(d>>5) + (d&31) + 1; rd=33g zero
constexpr int RS = 64;           // floats per Wt1 row (256 B)

// acc.x = w.x + acc.x ; acc.y = w.y + acc.y  (one VOP3P instruction)
__device__ __forceinline__ void pk_add(float2& acc, float2 w) {
    asm("v_pk_add_f32 %0, %1, %0" : "+v"(acc) : "v"(w));
}

// Wave-uniform L1 scan: mask m is an SGPR; per trip the SALU does
// ctz/clear/shift, the VALU does addr-add + pk_add, ds_read folds the
// row-base ((33g+1)*256 <= 42496) into its 16-bit offset immediate.
#define SCAN1(mask, g, acc) do {                                            \
    unsigned m_ = (mask);                                                   \
    while (m_) {                                                            \
        int f_ = __builtin_ctz(m_); m_ &= m_ - 1;                           \
        float2 w_ = *(const float2*)(vb1 + ((33 * (g) + 1) << 8) + (f_ << 8)); \
        pk_add((acc), w_);                                                  \
    }                                                                       \
} while (0)

// Wave-uniform L2 scan: rows of Wt2 are 64 B; rowbase*64 fits the imm.
#define SCAN2(mask, rowbase, acc) do {                                      \
    unsigned m_ = (mask);                                                   \
    while (m_) {                                                            \
        int f_ = __builtin_ctz(m_); m_ &= m_ - 1;                           \
        (acc) += *(const float*)(vb2 + ((rowbase) << 6) + (f_ << 6));       \
    }                                                                       \
} while (0)

__global__ __launch_bounds__(1024, 8)
void burst_snn_kernel(const float* __restrict__ x,
                      const float* __restrict__ W1,
                      const float* __restrict__ W2,
                      float* __restrict__ out, int B) {
    // Wt1 row layout (split-pair): floats {2l,2l+1} = {W[h=l], W[h=l+25]}, l<25.
    __shared__ float Wt1[ROWS1 * RS];   // 12352 floats = 48.25 KB
    // Wt2: 64 rows x 16 floats. rows 1..25: h=0..24; rows 27..51: h=25..49.
    __shared__ float Wt2[1024];         // 4 KB

    const int tid = threadIdx.x;
    for (int idx = tid; idx < ROWS1 * RS; idx += 1024) {
        int rd = idx >> 6, j = idx & 63;
        int g = rd / 33;
        bool zrow = (rd == 33 * g);
        int d = rd - 1 - g;
        int l = j >> 1;
        int h = (j & 1) ? (l + 25) : l;
        float v = 0.f;
        if (!zrow && l < 25) v = W1[h * D + d];
        Wt1[idx] = v;
    }
    {
        int r = tid >> 4, c = tid & 15;   // tid covers all 1024
        int h = -1;
        if (r >= 1 && r <= 25) h = r - 1;
        else if (r >= 27 && r <= 51) h = r - 2;
        float v = 0.f;
        if (h >= 0 && c < C) v = W2[c * H + h];
        Wt2[tid] = v;
    }
    __syncthreads();

    const int lane = tid & 63;
    const int laneH = lane & 31;
    const bool isLo = lane < 32;
    const int wave = tid >> 6;
    const int bA = blockIdx.x * EPB + wave * 2;
    const int b = isLo ? bA : (bA + 1);
    const bool active = b < B;

    const char* vb1 = (const char*)Wt1 + laneH * 8;       // float2 slot
    const char* vb2 = (const char*)Wt2 + (lane & 15) * 4; // col slot

    // Encoder registers: element's dims 32k + laneH in r_k (r5 valid laneH<27)
    float r0 = 0.f, r1 = 0.f, r2 = 0.f, r3 = 0.f, r4 = 0.f, r5 = 0.f;
    if (active) {
        const float* xb = x + (size_t)b * D;
        r0 = xb[laneH];
        r1 = xb[32 + laneH];
        r2 = xb[64 + laneH];
        r3 = xb[96 + laneH];
        r4 = xb[128 + laneH];
        if (laneH < D - 160) r5 = xb[160 + laneH];
    }
    float th0 = 0.125f, th1 = 0.125f, th2 = 0.125f;
    float th3 = 0.125f, th4 = 0.125f, th5 = 0.125f;
    float mem1x = 0.f, mem1y = 0.f;  // laneH 0..24: h = laneH / h = laneH+25
    float mem2 = 0.f;                // laneH 0..4: c = laneH
    int cntA = 0, cntB = 0;          // wave-uniform (SALU popcounts)

    float* outSpk = out;                     // [T][B][C]
    float* outCnt = out + (size_t)T * B * C; // [B]
    const unsigned BC = (unsigned)(B * C);
    unsigned o0 = (unsigned)(b * C + laneH); // only laneH < C stores
    int tDone = T;

    for (int t = 0; t < T; ++t) {
        // --- encoder, one step (exact fp32 sequence); ballots give BOTH
        //     elements' masks: lo 32 = A, hi 32 = B.
        bool s0 = r0 >= th0, s1 = r1 >= th1, s2 = r2 >= th2;
        bool s3 = r3 >= th3, s4 = r4 >= th4, s5 = r5 >= th5;
        r0 -= s0 ? th0 : 0.f; th0 = s0 ? th0 + th0 : 0.125f;
        r1 -= s1 ? th1 : 0.f; th1 = s1 ? th1 + th1 : 0.125f;
        r2 -= s2 ? th2 : 0.f; th2 = s2 ? th2 + th2 : 0.125f;
        r3 -= s3 ? th3 : 0.f; th3 = s3 ? th3 + th3 : 0.125f;
        r4 -= s4 ? th4 : 0.f; th4 = s4 ? th4 + th4 : 0.125f;
        r5 -= s5 ? th5 : 0.f; th5 = s5 ? th5 + th5 : 0.125f;
        unsigned long long E0 = __ballot(s0), E1 = __ballot(s1), E2 = __ballot(s2);
        unsigned long long E3 = __ballot(s3), E4 = __ballot(s4), E5 = __ballot(s5);
        unsigned mA0 = (unsigned)E0, mB0 = (unsigned)(E0 >> 32);
        unsigned mA1 = (unsigned)E1, mB1 = (unsigned)(E1 >> 32);
        unsigned mA2 = (unsigned)E2, mB2 = (unsigned)(E2 >> 32);
        unsigned mA3 = (unsigned)E3, mB3 = (unsigned)(E3 >> 32);
        unsigned mA4 = (unsigned)E4, mB4 = (unsigned)(E4 >> 32);
        unsigned mA5 = (unsigned)E5, mB5 = (unsigned)(E5 >> 32);
        cntA += __popc(mA0) + __popc(mA1) + __popc(mA2)
              + __popc(mA3) + __popc(mA4) + __popc(mA5);
        cntB += __popc(mB0) + __popc(mB1) + __popc(mB2)
              + __popc(mB3) + __popc(mB4) + __popc(mB5);

        // --- L1 gather, element A: 6 group scans (ascending-d within group),
        //     merge in the same pairwise-left order as R8/R9.
        float2 a0 = {0.f, 0.f}, a1 = {0.f, 0.f}, a2 = {0.f, 0.f};
        float2 a3 = {0.f, 0.f}, a4 = {0.f, 0.f}, a5 = {0.f, 0.f};
        SCAN1(mA0, 0, a0); SCAN1(mA1, 1, a1); SCAN1(mA2, 2, a2);
        SCAN1(mA3, 3, a3); SCAN1(mA4, 4, a4); SCAN1(mA5, 5, a5);
        float2 cmA = a0;
        pk_add(cmA, a1); pk_add(cmA, a2); pk_add(cmA, a3);
        pk_add(cmA, a4); pk_add(cmA, a5);
        // --- element B (reuse accumulators)
        a0 = {0.f, 0.f}; a1 = {0.f, 0.f}; a2 = {0.f, 0.f};
        a3 = {0.f, 0.f}; a4 = {0.f, 0.f}; a5 = {0.f, 0.f};
        SCAN1(mB0, 0, a0); SCAN1(mB1, 1, a1); SCAN1(mB2, 2, a2);
        SCAN1(mB3, 3, a3); SCAN1(mB4, 4, a4); SCAN1(mB5, 5, a5);
        float2 cmB = a0;
        pk_add(cmB, a1); pk_add(cmB, a2); pk_add(cmB, a3);
        pk_add(cmB, a4); pk_add(cmB, a5);

        float cx = isLo ? cmA.x : cmB.x;
        float cy = isLo ? cmA.y : cmB.y;

        // --- LIF layer 1 (both elements at once; valid laneH < 25)
        mem1x = 0.9f * mem1x + cx;
        bool spx = (mem1x - 1.0f > 0.f) && (laneH < 25);
        mem1x -= spx ? 1.0f : 0.f;
        mem1y = 0.9f * mem1y + cy;
        bool spy = (mem1y - 1.0f > 0.f) && (laneH < 25);
        mem1y -= spy ? 1.0f : 0.f;
        unsigned long long PX = __ballot(spx), PY = __ballot(spy);
        unsigned loA = (unsigned)PX & 0x1FFFFFFu;          // A, h<25
        unsigned loB = (unsigned)(PX >> 32) & 0x1FFFFFFu;  // B, h<25
        unsigned hiA = (unsigned)PY & 0x1FFFFFFu;          // A, h>=25
        unsigned hiB = (unsigned)(PY >> 32) & 0x1FFFFFFu;  // B, h>=25

        // --- L2 gather: wave-uniform scans; cur2 = (sum lo) + (sum hi),
        //     each ascending-h (same rounding as R8/R9's quarter scheme).
        float u0 = 0.f, u1 = 0.f, w0 = 0.f, w1 = 0.f;
        SCAN2(loA, 1, u0);  SCAN2(hiA, 27, u1);
        SCAN2(loB, 1, w0);  SCAN2(hiB, 27, w1);
        float cur2 = isLo ? (u0 + u1) : (w0 + w1);

        // --- LIF layer 2 + store (both elements; laneH < C)
        mem2 = 0.9f * mem2 + cur2;
        bool sp2 = (mem2 - 1.0f > 0.f);
        mem2 -= sp2 ? 1.0f : 0.f;
        if (active && laneH < C) outSpk[o0] = sp2 ? 1.0f : 0.0f;
        o0 += BC;

        // --- early exit: SALU quiet gate, then exact dead check (both elems).
        // Dead: all r < 0.125 (encoder permanently silent), all mem1 <= 1,
        // mem2 <= 1 -> every future output is exactly 0.0f.
        unsigned encAny = mA0 | mA1 | mA2 | mA3 | mA4 | mA5
                        | mB0 | mB1 | mB2 | mB3 | mB4 | mB5;
        if ((encAny | loA | hiA | loB | hiB) == 0u) {
            float rm = fmaxf(fmaxf(fmaxf(r0, r1), fmaxf(r2, r3)), fmaxf(r4, r5));
            unsigned long long am = __ballot(rm >= 0.125f);
            unsigned long long m1 =
                __ballot(fmaxf(mem1x, mem1y) > 1.0f) & 0x01FFFFFF01FFFFFFull;
            unsigned long long m2 = __ballot(mem2 > 1.0f) & 0x0000001F0000001Full;
            if ((am | m1 | m2) == 0ull) { tDone = t + 1; break; }
        }
    }

    // --- zero-fill the provably-silent tail steps
    if (active && laneH < C) {
        for (int tt = tDone; tt < T; ++tt) {
            outSpk[o0] = 0.0f;
            o0 += BC;
        }
    }
    // --- spike counts (wave-uniform SGPRs), one element per half-wave
    if (active && laneH == 0) outCnt[b] = (float)(isLo ? cntA : cntB);
}

extern "C" void kernel_launch(void* const* d_in, const int* in_sizes, int n_in,
                              void* d_out, int out_size, void* d_ws, size_t ws_size,
                              hipStream_t stream) {
    const float* x  = (const float*)d_in[0];
    const float* W1 = (const float*)d_in[1];
    const float* W2 = (const float*)d_in[2];
    float* out = (float*)d_out;
    const int B = in_sizes[0] / D;
    const int blocks = (B + EPB - 1) / EPB;
    burst_snn_kernel<<<blocks, 1024, 0, stream>>>(x, W1, W2, out, B);
}

// Round 3
// 125.077 us; speedup vs baseline: 1.4195x; 1.4195x over previous
//
#include <hip/hip_runtime.h>

// BurstSnn: 32-step burst-encoder + 2-layer LIF SNN, B=16384, D=187, H=50, C=5.
// R11 = R9 (103us dispatch, best) with the L1 gather restructured to
// QUARTER-WAVE float4 rows (R10's SGPR-scan regressed: uniform reads cover
// only 1 row/instr and SALU/branch serialization idled the VALU 28%).
//  - Wt1 row d = 16 float4 slots; slot l, comp c = W1[h=13c+l, d] (l<13).
//  - Quarters scan {even-groups@t, odd@t, even@t+1, odd@t+1}; one
//    ds_read_b128 per stream-trip = 4 row-reads. 18 VALU / 12 rows per trip
//    (1.5 VALU/row vs R9's 2.7), trips = max of 12 popcounts (vs sum of two
//    6-maxes).
//  - Odd-group partials merged to even-quarter lanes via ds_swizzle xor-16
//    (LDS pipe, no VALU); merge order ((((g0+g1)+g2)+g3)+g4)+g5 unchanged.
//  - LIF1 on float4 layout (lanes 0-12, h={l,13+l,26+l,39+l}); 4 component
//    ballots per step; h-ordered lo/hi masks rebuilt with shift-OR (the
//    h=13c+l layout makes this interleave-free).
//  - L2 quarter scan, LIF2, stores, early exit, counts: R9 verbatim.
// All arithmetic orders identical to R9 (absmax 0.0 preserved by construction).

constexpr int D = 187;
constexpr int H = 50;
constexpr int C = 5;
constexpr int T = 32;
constexpr int WPB = 16;        // waves per block
constexpr int ROWS1 = 193;     // rows rd = 33*(d>>5) + (d&31) + 1; rd=33g zero
constexpr int RS = 64;         // floats per Wt1 row (256 B): 16 float4 slots

__device__ __forceinline__ int v_ffbl(unsigned int m) {  // -1 when m == 0
    int r;
    asm("v_ffbl_b32 %0, %1" : "=v"(r) : "v"(m));
    return r;
}

// acc.x = w.x + acc.x ; acc.y = w.y + acc.y  (one VOP3P instruction)
__device__ __forceinline__ void pk_add(float2& acc, float2 w) {
    asm("v_pk_add_f32 %0, %1, %0" : "+v"(acc) : "v"(w));
}

// m = a*m + c  (per component, fused)
__device__ __forceinline__ void pk_fma(float2& m, float2 a, float2 c) {
    asm("v_pk_fma_f32 %0, %1, %0, %2" : "+v"(m) : "v"(a), "v"(c));
}

// lane l <-> l^16 within each 32-lane half (LDS pipe, no VALU)
__device__ __forceinline__ float2 sw16(float2 v) {
    float2 r;
    r.x = __int_as_float(__builtin_amdgcn_ds_swizzle(__float_as_int(v.x), 0x401F));
    r.y = __int_as_float(__builtin_amdgcn_ds_swizzle(__float_as_int(v.y), 0x401F));
    return r;
}

__global__ __launch_bounds__(1024, 8)
void burst_snn_kernel(const float* __restrict__ x,
                      const float* __restrict__ W1,
                      const float* __restrict__ W2,
                      float* __restrict__ out, int B) {
    __shared__ float Wt1[ROWS1 * RS];   // 12352 floats = 48.25 KB
    // Wt2: 64 rows x 16 floats. rows 1..25: h=0..24; rows 27..51: h=25..49.
    __shared__ float Wt2[1024];         // 4 KB

    const int tid = threadIdx.x;
    for (int idx = tid; idx < ROWS1 * RS; idx += 1024) {
        int rd = idx >> 6, j = idx & 63;
        int g = rd / 33;
        bool zrow = (rd == 33 * g);
        int d = rd - 1 - g;
        int slot = j >> 2, c = j & 3;
        int h = 13 * c + slot;
        float v = 0.f;
        if (!zrow && slot < 13 && h < H) v = W1[h * D + d];
        Wt1[idx] = v;
    }
    {
        int r = tid >> 4, c = tid & 15;   // tid covers all 1024
        int h = -1;
        if (r >= 1 && r <= 25) h = r - 1;
        else if (r >= 27 && r <= 51) h = r - 2;
        float v = 0.f;
        if (h >= 0 && c < C) v = W2[c * H + h];
        Wt2[tid] = v;
    }
    __syncthreads();

    const int lane = tid & 63;
    const int b = blockIdx.x * WPB + (tid >> 6);
    const bool active = b < B;
    const bool isLo = lane < 32;
    const int qOdd = (lane >> 4) & 1;    // quarters 1,3 handle odd groups
    const int ql = lane & 15;            // float4 slot within a row (ql<13 live)

    // Gather bases: stream s covers groups {2s (even quarters), 2s+1 (odd)}.
    // Row base = 33*(2s+qOdd)+1 (the +1 makes f=-1 land on zero row 33g).
    const char* wb = (const char*)Wt1;
    const int qbase = ql * 16 + (qOdd ? (33 << 8) : 0) + 256;
    const char* bs0 = wb + qbase;               // groups 0/1
    const char* bs1 = wb + qbase + (66 << 8);   // groups 2/3
    const char* bs2 = wb + qbase + (132 << 8);  // groups 4/5

    // L2 quarter scan: q0..q3 scan {lo_t, hi_t, lo_u, hi_u}.
    const float* base2 = Wt2 + ((qOdd ? 27 : 1) << 4) + ql;

    // Encoder registers: dims lane, lane+64, lane+128 (3rd valid for lane<59)
    float r0 = 0.f, r1 = 0.f, r2 = 0.f;
    if (active) {
        const float* xb = x + (size_t)b * D;
        r0 = xb[lane];
        r1 = xb[64 + lane];
        if (lane < D - 128) r2 = xb[128 + lane];
    }
    float th0 = 0.125f, th1 = 0.125f, th2 = 0.125f;
    // LIF1 membranes, lanes 0..12: comps = h {ql, 13+ql, 26+ql, 39+ql}
    float2 m01 = make_float2(0.f, 0.f), m23 = make_float2(0.f, 0.f);
    float mem2 = 0.f;                // lanes 0..4: c = lane
    int cnt = 0;                     // wave-uniform (SALU popcounts)

    const float2 beta2 = make_float2(0.9f, 0.9f);
    const float2 neg1 = make_float2(-1.0f, -1.0f);

    float* outSpk = out;                     // [T][B][C]
    float* outCnt = out + (size_t)T * B * C; // [B]
    const unsigned BC = (unsigned)(B * C);
    unsigned o0 = (unsigned)(b * C + lane);  // only lanes < C store

    unsigned int ga[6], gb[6];
    int tDone = T;

    for (int t = 0; t < T; t += 2) {
        // --- two encoder steps (exact fp32 sequence), masks for t and t+1
        {
            bool s0 = r0 >= th0, s1 = r1 >= th1, s2 = r2 >= th2;
            r0 -= s0 ? th0 : 0.f; th0 = s0 ? th0 + th0 : 0.125f;
            r1 -= s1 ? th1 : 0.f; th1 = s1 ? th1 + th1 : 0.125f;
            r2 -= s2 ? th2 : 0.f; th2 = s2 ? th2 + th2 : 0.125f;
            unsigned long long B0 = __ballot(s0), B1 = __ballot(s1), B2 = __ballot(s2);
            ga[0] = (unsigned)B0; ga[1] = (unsigned)(B0 >> 32);
            ga[2] = (unsigned)B1; ga[3] = (unsigned)(B1 >> 32);
            ga[4] = (unsigned)B2; ga[5] = (unsigned)(B2 >> 32);
        }
        {
            bool s0 = r0 >= th0, s1 = r1 >= th1, s2 = r2 >= th2;
            r0 -= s0 ? th0 : 0.f; th0 = s0 ? th0 + th0 : 0.125f;
            r1 -= s1 ? th1 : 0.f; th1 = s1 ? th1 + th1 : 0.125f;
            r2 -= s2 ? th2 : 0.f; th2 = s2 ? th2 + th2 : 0.125f;
            unsigned long long B0 = __ballot(s0), B1 = __ballot(s1), B2 = __ballot(s2);
            gb[0] = (unsigned)B0; gb[1] = (unsigned)(B0 >> 32);
            gb[2] = (unsigned)B1; gb[3] = (unsigned)(B1 >> 32);
            gb[4] = (unsigned)B2; gb[5] = (unsigned)(B2 >> 32);
        }

        // SALU: spike count + trip count (max of all 12 popcounts)
        int pa0 = __popc(ga[0]), pa1 = __popc(ga[1]), pa2 = __popc(ga[2]);
        int pa3 = __popc(ga[3]), pa4 = __popc(ga[4]), pa5 = __popc(ga[5]);
        int pb0 = __popc(gb[0]), pb1 = __popc(gb[1]), pb2 = __popc(gb[2]);
        int pb3 = __popc(gb[3]), pb4 = __popc(gb[4]), pb5 = __popc(gb[5]);
        cnt += pa0 + pa1 + pa2 + pa3 + pa4 + pa5
             + pb0 + pb1 + pb2 + pb3 + pb4 + pb5;
        int n = pa0 > pa1 ? pa0 : pa1;
        n = n > pa2 ? n : pa2;  n = n > pa3 ? n : pa3;
        n = n > pa4 ? n : pa4;  n = n > pa5 ? n : pa5;
        n = n > pb0 ? n : pb0;  n = n > pb1 ? n : pb1;
        n = n > pb2 ? n : pb2;  n = n > pb3 ? n : pb3;
        n = n > pb4 ? n : pb4;  n = n > pb5 ? n : pb5;

        // Per-lane stream masks: quarter q scans (group 2s+qOdd, step t/u)
        unsigned e0 = isLo ? ga[0] : gb[0], d0 = isLo ? ga[1] : gb[1];
        unsigned e1 = isLo ? ga[2] : gb[2], d1 = isLo ? ga[3] : gb[3];
        unsigned e2 = isLo ? ga[4] : gb[4], d2 = isLo ? ga[5] : gb[5];
        unsigned vm0 = qOdd ? d0 : e0;
        unsigned vm1 = qOdd ? d1 : e1;
        unsigned vm2 = qOdd ? d2 : e2;

        // --- L1 gather: 3 streams, 1 ds_read_b128 per stream-trip = 4 rows
        float2 a0l = {0.f, 0.f}, a0h = {0.f, 0.f};
        float2 a1l = {0.f, 0.f}, a1h = {0.f, 0.f};
        float2 a2l = {0.f, 0.f}, a2h = {0.f, 0.f};
        for (; n > 0; --n) {
            int f0 = v_ffbl(vm0); vm0 &= vm0 - 1;
            int f1 = v_ffbl(vm1); vm1 &= vm1 - 1;
            int f2 = v_ffbl(vm2); vm2 &= vm2 - 1;
            const char* p0 = bs0 + (f0 << 8);
            const char* p1 = bs1 + (f1 << 8);
            const char* p2 = bs2 + (f2 << 8);
            float2 w0l = *(const float2*)p0, w0h = *(const float2*)(p0 + 8);
            float2 w1l = *(const float2*)p1, w1h = *(const float2*)(p1 + 8);
            float2 w2l = *(const float2*)p2, w2h = *(const float2*)(p2 + 8);
            pk_add(a0l, w0l); pk_add(a0h, w0h);
            pk_add(a1l, w1l); pk_add(a1h, w1h);
            pk_add(a2l, w2l); pk_add(a2h, w2h);
        }

        // --- merge: bring odd-group partials to even-quarter lanes (swizzle
        //     handles q1->q0 and q3->q2 at once); order g0..g5 pairwise-left.
        float2 s0l = sw16(a0l), s0h = sw16(a0h);
        float2 s1l = sw16(a1l), s1h = sw16(a1h);
        float2 s2l = sw16(a2l), s2h = sw16(a2h);
        float2 cml = a0l, cmh = a0h;
        pk_add(cml, s0l); pk_add(cmh, s0h);   // +g1
        pk_add(cml, a1l); pk_add(cmh, a1h);   // +g2
        pk_add(cml, s1l); pk_add(cmh, s1h);   // +g3
        pk_add(cml, a2l); pk_add(cmh, a2h);   // +g4
        pk_add(cml, s2l); pk_add(cmh, s2h);   // +g5
        // cml/cmh: cur1 float4 on lanes 0-12 (step t) and 32-44 (step t+1)
        float2 cu01 = make_float2(__shfl_down(cml.x, 32), __shfl_down(cml.y, 32));
        float2 cu23 = make_float2(__shfl_down(cmh.x, 32), __shfl_down(cmh.y, 32));

        // --- LIF layer 1, step t (lanes 0-12; pads have zero weights)
        pk_fma(m01, beta2, cml);
        pk_fma(m23, beta2, cmh);
        float2 d01 = m01, d23 = m23;
        pk_add(d01, neg1); pk_add(d23, neg1);
        bool t0 = d01.x > 0.f, t1 = d01.y > 0.f;
        bool t2 = d23.x > 0.f, t3 = d23.y > 0.f;
        unsigned long long Pa = __ballot(t0), Pb = __ballot(t1);
        unsigned long long Pc = __ballot(t2), Pd = __ballot(t3);
        m01.x = t0 ? d01.x : m01.x;  m01.y = t1 ? d01.y : m01.y;
        m23.x = t2 ? d23.x : m23.x;  m23.y = t3 ? d23.y : m23.y;
        unsigned c0t = (unsigned)Pa & 0x1FFFu;
        unsigned c1t = (unsigned)Pb & 0x1FFFu;
        unsigned c2t = (unsigned)Pc & 0x1FFFu;
        unsigned c3t = (unsigned)Pd & 0x1FFFu;
        // --- LIF layer 1, step t+1
        pk_fma(m01, beta2, cu01);
        pk_fma(m23, beta2, cu23);
        float2 e01 = m01, e23 = m23;
        pk_add(e01, neg1); pk_add(e23, neg1);
        bool u0 = e01.x > 0.f, u1 = e01.y > 0.f;
        bool u2 = e23.x > 0.f, u3 = e23.y > 0.f;
        unsigned long long Qa = __ballot(u0), Qb = __ballot(u1);
        unsigned long long Qc = __ballot(u2), Qd = __ballot(u3);
        m01.x = u0 ? e01.x : m01.x;  m01.y = u1 ? e01.y : m01.y;
        m23.x = u2 ? e23.x : m23.x;  m23.y = u3 ? e23.y : m23.y;
        unsigned c0u = (unsigned)Qa & 0x1FFFu;
        unsigned c1u = (unsigned)Qb & 0x1FFFu;
        unsigned c2u = (unsigned)Qc & 0x1FFFu;
        unsigned c3u = (unsigned)Qd & 0x1FFFu;

        // h-ordered spike masks (h = 13c + l): shift-OR only, no interleave
        unsigned lo_t = c0t | ((c1t & 0xFFFu) << 13);           // h 0..24
        unsigned hi_t = (c1t >> 12) | (c2t << 1) | ((c3t & 0x7FFu) << 14); // h 25..49
        unsigned lo_u = c0u | ((c1u & 0xFFFu) << 13);
        unsigned hi_u = (c1u >> 12) | (c2u << 1) | ((c3u & 0x7FFu) << 14);

        // --- layer-2 quarter-wave gather (R9 verbatim): q0..q3 scan
        //     {lo_t,hi_t,lo_u,hi_u}; one ds_read_b32 covers 4 spikes.
        int p0c = __popc(lo_t), p1c = __popc(hi_t);
        int p2c = __popc(lo_u), p3c = __popc(hi_u);
        int n2 = p0c > p1c ? p0c : p1c;
        n2 = n2 > p2c ? n2 : p2c;
        n2 = n2 > p3c ? n2 : p3c;
        float cq = 0.f;
        if (n2) {
            unsigned vmq = isLo ? (qOdd ? hi_t : lo_t) : (qOdd ? hi_u : lo_u);
            for (; n2 > 0; --n2) {
                int f = v_ffbl(vmq); vmq &= vmq - 1;
                cq += *(base2 + f * 16);
            }
        }
        // combine quarters: lanes 0..4 get (lo+hi) for t; +32 lanes for t+1
        float tmp = cq + __shfl_down(cq, 16);
        float cur2 = tmp;                              // step t   (lanes 0..4)
        float c2t1 = __shfl_down(tmp, 32);             // step t+1 -> lanes 0..4

        // --- LIF layer 2, step t
        mem2 = 0.9f * mem2 + cur2;
        bool sp2 = (mem2 - 1.0f > 0.f);
        mem2 -= sp2 ? 1.0f : 0.f;
        if (active && lane < C) outSpk[o0] = sp2 ? 1.0f : 0.0f;
        // --- LIF layer 2, step t+1
        mem2 = 0.9f * mem2 + c2t1;
        bool sp2b = (mem2 - 1.0f > 0.f);
        mem2 -= sp2b ? 1.0f : 0.f;
        if (active && lane < C) outSpk[o0 + BC] = sp2b ? 1.0f : 0.0f;
        o0 += 2u * BC;

        // --- early exit: SALU quiet gate, then exact dead check.
        unsigned encAny = ga[0] | ga[1] | ga[2] | ga[3] | ga[4] | ga[5]
                        | gb[0] | gb[1] | gb[2] | gb[3] | gb[4] | gb[5];
        unsigned l1Any = lo_t | hi_t | lo_u | hi_u;
        if ((encAny | l1Any) == 0u) {
            float rm = fmaxf(fmaxf(r0, r1), r2);        // residuals are >= 0
            unsigned long long am = __ballot(rm >= 0.125f);
            float mm = fmaxf(fmaxf(m01.x, m01.y), fmaxf(m23.x, m23.y));
            unsigned long long m1 = __ballot(mm > 1.0f) & 0x1FFFull;
            unsigned long long m2 = __ballot(mem2 > 1.0f) & 0x1Full;
            if ((am | m1 | m2) == 0ull) { tDone = t + 2; break; }
        }
    }

    // --- zero-fill the provably-silent tail steps
    if (active && lane < C) {
        for (int tt = tDone; tt < T; ++tt) {
            outSpk[o0] = 0.0f;
            o0 += BC;
        }
    }
    // --- spike count (wave-uniform), write counts[b]
    if (active && lane == 0) outCnt[b] = (float)cnt;
}

extern "C" void kernel_launch(void* const* d_in, const int* in_sizes, int n_in,
                              void* d_out, int out_size, void* d_ws, size_t ws_size,
                              hipStream_t stream) {
    const float* x  = (const float*)d_in[0];
    const float* W1 = (const float*)d_in[1];
    const float* W2 = (const float*)d_in[2];
    float* out = (float*)d_out;
    const int B = in_sizes[0] / D;
    const int blocks = (B + WPB - 1) / WPB;
    burst_snn_kernel<<<blocks, 1024, 0, stream>>>(x, W1, W2, out, B);
}

// Round 4
// 121.290 us; speedup vs baseline: 1.4638x; 1.0312x over previous
//
#include <hip/hip_runtime.h>

// BurstSnn: 32-step burst-encoder + 2-layer LIF SNN, B=16384, D=187, H=50, C=5.
// R12 = R11 (74.5us dispatch, VALUBusy ~90%, VALU-count-bound) + DENSE-MODE
// gather for high-density iterations (in practice iteration 0, where encoder
// spike prob is 0.875/0.62 -> n~29-31 of 32):
//  - when trip count n >= 21, skip bit-scanning entirely: fully-unrolled scan
//    of all 32 rows per stream with compile-time ds_read offset immediates
//    (no ffbl / mask-clear / address VALU), multiplying each row by the
//    spike bit as a float via v_pk_fma_f32 with op_sel_hi:[0,1,1] (scalar
//    broadcast from the pair's low half). 12 VALU/trip vs sparse 18.
//  - bit-exact: f ascends 0..31 (same order as ffbl scan); 1.0*w+acc rounds
//    identically to acc+w; +-0.0 contributions leave acc unchanged (acc is
//    never -0.0: starts +0.0, sums of nonzero finite values can't yield -0.0
//    under RN). Group-5 out-of-range rows have zero mask bits and their
//    reads stay inside the LDS block (max offset 50688 < 53760).
// Everything else (quarter-wave float4 gather, swizzle merge, LIF, L2 scan,
// early exit) unchanged from R11.

constexpr int D = 187;
constexpr int H = 50;
constexpr int C = 5;
constexpr int T = 32;
constexpr int WPB = 16;        // waves per block
constexpr int ROWS1 = 193;     // rows rd = 33*(d>>5) + (d&31) + 1; rd=33g zero
constexpr int RS = 64;         // floats per Wt1 row (256 B): 16 float4 slots

__device__ __forceinline__ int v_ffbl(unsigned int m) {  // -1 when m == 0
    int r;
    asm("v_ffbl_b32 %0, %1" : "=v"(r) : "v"(m));
    return r;
}

// acc.x = w.x + acc.x ; acc.y = w.y + acc.y  (one VOP3P instruction)
__device__ __forceinline__ void pk_add(float2& acc, float2 w) {
    asm("v_pk_add_f32 %0, %1, %0" : "+v"(acc) : "v"(w));
}

// m = a*m + c  (per component, fused)
__device__ __forceinline__ void pk_fma(float2& m, float2 a, float2 c) {
    asm("v_pk_fma_f32 %0, %1, %0, %2" : "+v"(m) : "v"(a), "v"(c));
}

// acc = s.lo * w + acc  (scalar broadcast via op_sel_hi: hi result uses
// src0's LOW half; s.y is never read by the hardware)
__device__ __forceinline__ void pk_fma_b(float2& acc, float2 s, float2 w) {
    asm("v_pk_fma_f32 %0, %2, %1, %0 op_sel:[0,0,0] op_sel_hi:[0,1,1]"
        : "+v"(acc) : "v"(w), "v"(s));
}

// lane l <-> l^16 within each 32-lane half (LDS pipe, no VALU)
__device__ __forceinline__ float2 sw16(float2 v) {
    float2 r;
    r.x = __int_as_float(__builtin_amdgcn_ds_swizzle(__float_as_int(v.x), 0x401F));
    r.y = __int_as_float(__builtin_amdgcn_ds_swizzle(__float_as_int(v.y), 0x401F));
    return r;
}

__global__ __launch_bounds__(1024, 8)
void burst_snn_kernel(const float* __restrict__ x,
                      const float* __restrict__ W1,
                      const float* __restrict__ W2,
                      float* __restrict__ out, int B) {
    __shared__ float Wt1[ROWS1 * RS];   // 12352 floats = 48.25 KB
    // Wt2: 64 rows x 16 floats. rows 1..25: h=0..24; rows 27..51: h=25..49.
    __shared__ float Wt2[1024];         // 4 KB

    const int tid = threadIdx.x;
    for (int idx = tid; idx < ROWS1 * RS; idx += 1024) {
        int rd = idx >> 6, j = idx & 63;
        int g = rd / 33;
        bool zrow = (rd == 33 * g);
        int d = rd - 1 - g;
        int slot = j >> 2, c = j & 3;
        int h = 13 * c + slot;
        float v = 0.f;
        if (!zrow && slot < 13 && h < H) v = W1[h * D + d];
        Wt1[idx] = v;
    }
    {
        int r = tid >> 4, c = tid & 15;   // tid covers all 1024
        int h = -1;
        if (r >= 1 && r <= 25) h = r - 1;
        else if (r >= 27 && r <= 51) h = r - 2;
        float v = 0.f;
        if (h >= 0 && c < C) v = W2[c * H + h];
        Wt2[tid] = v;
    }
    __syncthreads();

    const int lane = tid & 63;
    const int b = blockIdx.x * WPB + (tid >> 6);
    const bool active = b < B;
    const bool isLo = lane < 32;
    const int qOdd = (lane >> 4) & 1;    // quarters 1,3 handle odd groups
    const int ql = lane & 15;            // float4 slot within a row (ql<13 live)

    // Gather bases: stream s covers groups {2s (even quarters), 2s+1 (odd)}.
    // Row base = 33*(2s+qOdd)+1 (the +1 makes f=-1 land on zero row 33g).
    const char* wb = (const char*)Wt1;
    const int qbase = ql * 16 + (qOdd ? (33 << 8) : 0) + 256;
    const char* bs0 = wb + qbase;               // groups 0/1
    const char* bs1 = wb + qbase + (66 << 8);   // groups 2/3
    const char* bs2 = wb + qbase + (132 << 8);  // groups 4/5

    // L2 quarter scan: q0..q3 scan {lo_t, hi_t, lo_u, hi_u}.
    const float* base2 = Wt2 + ((qOdd ? 27 : 1) << 4) + ql;

    // Encoder registers: dims lane, lane+64, lane+128 (3rd valid for lane<59)
    float r0 = 0.f, r1 = 0.f, r2 = 0.f;
    if (active) {
        const float* xb = x + (size_t)b * D;
        r0 = xb[lane];
        r1 = xb[64 + lane];
        if (lane < D - 128) r2 = xb[128 + lane];
    }
    float th0 = 0.125f, th1 = 0.125f, th2 = 0.125f;
    // LIF1 membranes, lanes 0..12: comps = h {ql, 13+ql, 26+ql, 39+ql}
    float2 m01 = make_float2(0.f, 0.f), m23 = make_float2(0.f, 0.f);
    float mem2 = 0.f;                // lanes 0..4: c = lane
    int cnt = 0;                     // wave-uniform (SALU popcounts)

    const float2 beta2 = make_float2(0.9f, 0.9f);
    const float2 neg1 = make_float2(-1.0f, -1.0f);

    float* outSpk = out;                     // [T][B][C]
    float* outCnt = out + (size_t)T * B * C; // [B]
    const unsigned BC = (unsigned)(B * C);
    unsigned o0 = (unsigned)(b * C + lane);  // only lanes < C store

    unsigned int ga[6], gb[6];
    int tDone = T;

    for (int t = 0; t < T; t += 2) {
        // --- two encoder steps (exact fp32 sequence), masks for t and t+1
        {
            bool s0 = r0 >= th0, s1 = r1 >= th1, s2 = r2 >= th2;
            r0 -= s0 ? th0 : 0.f; th0 = s0 ? th0 + th0 : 0.125f;
            r1 -= s1 ? th1 : 0.f; th1 = s1 ? th1 + th1 : 0.125f;
            r2 -= s2 ? th2 : 0.f; th2 = s2 ? th2 + th2 : 0.125f;
            unsigned long long B0 = __ballot(s0), B1 = __ballot(s1), B2 = __ballot(s2);
            ga[0] = (unsigned)B0; ga[1] = (unsigned)(B0 >> 32);
            ga[2] = (unsigned)B1; ga[3] = (unsigned)(B1 >> 32);
            ga[4] = (unsigned)B2; ga[5] = (unsigned)(B2 >> 32);
        }
        {
            bool s0 = r0 >= th0, s1 = r1 >= th1, s2 = r2 >= th2;
            r0 -= s0 ? th0 : 0.f; th0 = s0 ? th0 + th0 : 0.125f;
            r1 -= s1 ? th1 : 0.f; th1 = s1 ? th1 + th1 : 0.125f;
            r2 -= s2 ? th2 : 0.f; th2 = s2 ? th2 + th2 : 0.125f;
            unsigned long long B0 = __ballot(s0), B1 = __ballot(s1), B2 = __ballot(s2);
            gb[0] = (unsigned)B0; gb[1] = (unsigned)(B0 >> 32);
            gb[2] = (unsigned)B1; gb[3] = (unsigned)(B1 >> 32);
            gb[4] = (unsigned)B2; gb[5] = (unsigned)(B2 >> 32);
        }

        // SALU: spike count + trip count (max of all 12 popcounts)
        int pa0 = __popc(ga[0]), pa1 = __popc(ga[1]), pa2 = __popc(ga[2]);
        int pa3 = __popc(ga[3]), pa4 = __popc(ga[4]), pa5 = __popc(ga[5]);
        int pb0 = __popc(gb[0]), pb1 = __popc(gb[1]), pb2 = __popc(gb[2]);
        int pb3 = __popc(gb[3]), pb4 = __popc(gb[4]), pb5 = __popc(gb[5]);
        cnt += pa0 + pa1 + pa2 + pa3 + pa4 + pa5
             + pb0 + pb1 + pb2 + pb3 + pb4 + pb5;
        int n = pa0 > pa1 ? pa0 : pa1;
        n = n > pa2 ? n : pa2;  n = n > pa3 ? n : pa3;
        n = n > pa4 ? n : pa4;  n = n > pa5 ? n : pa5;
        n = n > pb0 ? n : pb0;  n = n > pb1 ? n : pb1;
        n = n > pb2 ? n : pb2;  n = n > pb3 ? n : pb3;
        n = n > pb4 ? n : pb4;  n = n > pb5 ? n : pb5;

        // Per-lane stream masks: quarter q scans (group 2s+qOdd, step t/u)
        unsigned e0 = isLo ? ga[0] : gb[0], d0 = isLo ? ga[1] : gb[1];
        unsigned e1 = isLo ? ga[2] : gb[2], d1 = isLo ? ga[3] : gb[3];
        unsigned e2 = isLo ? ga[4] : gb[4], d2 = isLo ? ga[5] : gb[5];
        unsigned vm0 = qOdd ? d0 : e0;
        unsigned vm1 = qOdd ? d1 : e1;
        unsigned vm2 = qOdd ? d2 : e2;

        // --- L1 gather
        float2 a0l = {0.f, 0.f}, a0h = {0.f, 0.f};
        float2 a1l = {0.f, 0.f}, a1h = {0.f, 0.f};
        float2 a2l = {0.f, 0.f}, a2h = {0.f, 0.f};
        if (n >= 21) {
            // DENSE: unconditional full scan, offsets are compile-time
            // immediates, spike bit -> {0.0,1.0} multiplier (broadcast fma).
            float2 sv0 = {0.f, 0.f}, sv1 = {0.f, 0.f}, sv2 = {0.f, 0.f};
            #pragma unroll
            for (int f = 0; f < 32; ++f) {
                sv0.x = (float)((vm0 >> f) & 1u);
                sv1.x = (float)((vm1 >> f) & 1u);
                sv2.x = (float)((vm2 >> f) & 1u);
                const char* p0 = bs0 + (f << 8);
                const char* p1 = bs1 + (f << 8);
                const char* p2 = bs2 + (f << 8);
                float2 w0l = *(const float2*)p0, w0h = *(const float2*)(p0 + 8);
                float2 w1l = *(const float2*)p1, w1h = *(const float2*)(p1 + 8);
                float2 w2l = *(const float2*)p2, w2h = *(const float2*)(p2 + 8);
                pk_fma_b(a0l, sv0, w0l); pk_fma_b(a0h, sv0, w0h);
                pk_fma_b(a1l, sv1, w1l); pk_fma_b(a1h, sv1, w1h);
                pk_fma_b(a2l, sv2, w2l); pk_fma_b(a2h, sv2, w2h);
            }
        } else {
            // SPARSE: 3 streams, 1 ds_read_b128 per stream-trip = 4 rows
            for (; n > 0; --n) {
                int f0 = v_ffbl(vm0); vm0 &= vm0 - 1;
                int f1 = v_ffbl(vm1); vm1 &= vm1 - 1;
                int f2 = v_ffbl(vm2); vm2 &= vm2 - 1;
                const char* p0 = bs0 + (f0 << 8);
                const char* p1 = bs1 + (f1 << 8);
                const char* p2 = bs2 + (f2 << 8);
                float2 w0l = *(const float2*)p0, w0h = *(const float2*)(p0 + 8);
                float2 w1l = *(const float2*)p1, w1h = *(const float2*)(p1 + 8);
                float2 w2l = *(const float2*)p2, w2h = *(const float2*)(p2 + 8);
                pk_add(a0l, w0l); pk_add(a0h, w0h);
                pk_add(a1l, w1l); pk_add(a1h, w1h);
                pk_add(a2l, w2l); pk_add(a2h, w2h);
            }
        }

        // --- merge: bring odd-group partials to even-quarter lanes (swizzle
        //     handles q1->q0 and q3->q2 at once); order g0..g5 pairwise-left.
        float2 s0l = sw16(a0l), s0h = sw16(a0h);
        float2 s1l = sw16(a1l), s1h = sw16(a1h);
        float2 s2l = sw16(a2l), s2h = sw16(a2h);
        float2 cml = a0l, cmh = a0h;
        pk_add(cml, s0l); pk_add(cmh, s0h);   // +g1
        pk_add(cml, a1l); pk_add(cmh, a1h);   // +g2
        pk_add(cml, s1l); pk_add(cmh, s1h);   // +g3
        pk_add(cml, a2l); pk_add(cmh, a2h);   // +g4
        pk_add(cml, s2l); pk_add(cmh, s2h);   // +g5
        // cml/cmh: cur1 float4 on lanes 0-12 (step t) and 32-44 (step t+1)
        float2 cu01 = make_float2(__shfl_down(cml.x, 32), __shfl_down(cml.y, 32));
        float2 cu23 = make_float2(__shfl_down(cmh.x, 32), __shfl_down(cmh.y, 32));

        // --- LIF layer 1, step t (lanes 0-12; pads have zero weights)
        pk_fma(m01, beta2, cml);
        pk_fma(m23, beta2, cmh);
        float2 d01 = m01, d23 = m23;
        pk_add(d01, neg1); pk_add(d23, neg1);
        bool t0 = d01.x > 0.f, t1 = d01.y > 0.f;
        bool t2 = d23.x > 0.f, t3 = d23.y > 0.f;
        unsigned long long Pa = __ballot(t0), Pb = __ballot(t1);
        unsigned long long Pc = __ballot(t2), Pd = __ballot(t3);
        m01.x = t0 ? d01.x : m01.x;  m01.y = t1 ? d01.y : m01.y;
        m23.x = t2 ? d23.x : m23.x;  m23.y = t3 ? d23.y : m23.y;
        unsigned c0t = (unsigned)Pa & 0x1FFFu;
        unsigned c1t = (unsigned)Pb & 0x1FFFu;
        unsigned c2t = (unsigned)Pc & 0x1FFFu;
        unsigned c3t = (unsigned)Pd & 0x1FFFu;
        // --- LIF layer 1, step t+1
        pk_fma(m01, beta2, cu01);
        pk_fma(m23, beta2, cu23);
        float2 e01 = m01, e23 = m23;
        pk_add(e01, neg1); pk_add(e23, neg1);
        bool u0 = e01.x > 0.f, u1 = e01.y > 0.f;
        bool u2 = e23.x > 0.f, u3 = e23.y > 0.f;
        unsigned long long Qa = __ballot(u0), Qb = __ballot(u1);
        unsigned long long Qc = __ballot(u2), Qd = __ballot(u3);
        m01.x = u0 ? e01.x : m01.x;  m01.y = u1 ? e01.y : m01.y;
        m23.x = u2 ? e23.x : m23.x;  m23.y = u3 ? e23.y : m23.y;
        unsigned c0u = (unsigned)Qa & 0x1FFFu;
        unsigned c1u = (unsigned)Qb & 0x1FFFu;
        unsigned c2u = (unsigned)Qc & 0x1FFFu;
        unsigned c3u = (unsigned)Qd & 0x1FFFu;

        // h-ordered spike masks (h = 13c + l): shift-OR only, no interleave
        unsigned lo_t = c0t | ((c1t & 0xFFFu) << 13);           // h 0..24
        unsigned hi_t = (c1t >> 12) | (c2t << 1) | ((c3t & 0x7FFu) << 14); // h 25..49
        unsigned lo_u = c0u | ((c1u & 0xFFFu) << 13);
        unsigned hi_u = (c1u >> 12) | (c2u << 1) | ((c3u & 0x7FFu) << 14);

        // --- layer-2 quarter-wave gather: q0..q3 scan {lo_t,hi_t,lo_u,hi_u}
        int p0c = __popc(lo_t), p1c = __popc(hi_t);
        int p2c = __popc(lo_u), p3c = __popc(hi_u);
        int n2 = p0c > p1c ? p0c : p1c;
        n2 = n2 > p2c ? n2 : p2c;
        n2 = n2 > p3c ? n2 : p3c;
        float cq = 0.f;
        if (n2) {
            unsigned vmq = isLo ? (qOdd ? hi_t : lo_t) : (qOdd ? hi_u : lo_u);
            for (; n2 > 0; --n2) {
                int f = v_ffbl(vmq); vmq &= vmq - 1;
                cq += *(base2 + f * 16);
            }
        }
        // combine quarters: lanes 0..4 get (lo+hi) for t; +32 lanes for t+1
        float tmp = cq + __shfl_down(cq, 16);
        float cur2 = tmp;                              // step t   (lanes 0..4)
        float c2t1 = __shfl_down(tmp, 32);             // step t+1 -> lanes 0..4

        // --- LIF layer 2, step t
        mem2 = 0.9f * mem2 + cur2;
        bool sp2 = (mem2 - 1.0f > 0.f);
        mem2 -= sp2 ? 1.0f : 0.f;
        if (active && lane < C) outSpk[o0] = sp2 ? 1.0f : 0.0f;
        // --- LIF layer 2, step t+1
        mem2 = 0.9f * mem2 + c2t1;
        bool sp2b = (mem2 - 1.0f > 0.f);
        mem2 -= sp2b ? 1.0f : 0.f;
        if (active && lane < C) outSpk[o0 + BC] = sp2b ? 1.0f : 0.0f;
        o0 += 2u * BC;

        // --- early exit: SALU quiet gate, then exact dead check.
        unsigned encAny = ga[0] | ga[1] | ga[2] | ga[3] | ga[4] | ga[5]
                        | gb[0] | gb[1] | gb[2] | gb[3] | gb[4] | gb[5];
        unsigned l1Any = lo_t | hi_t | lo_u | hi_u;
        if ((encAny | l1Any) == 0u) {
            float rm = fmaxf(fmaxf(r0, r1), r2);        // residuals are >= 0
            unsigned long long am = __ballot(rm >= 0.125f);
            float mm = fmaxf(fmaxf(m01.x, m01.y), fmaxf(m23.x, m23.y));
            unsigned long long m1 = __ballot(mm > 1.0f) & 0x1FFFull;
            unsigned long long m2 = __ballot(mem2 > 1.0f) & 0x1Full;
            if ((am | m1 | m2) == 0ull) { tDone = t + 2; break; }
        }
    }

    // --- zero-fill the provably-silent tail steps
    if (active && lane < C) {
        for (int tt = tDone; tt < T; ++tt) {
            outSpk[o0] = 0.0f;
            o0 += BC;
        }
    }
    // --- spike count (wave-uniform), write counts[b]
    if (active && lane == 0) outCnt[b] = (float)cnt;
}

extern "C" void kernel_launch(void* const* d_in, const int* in_sizes, int n_in,
                              void* d_out, int out_size, void* d_ws, size_t ws_size,
                              hipStream_t stream) {
    const float* x  = (const float*)d_in[0];
    const float* W1 = (const float*)d_in[1];
    const float* W2 = (const float*)d_in[2];
    float* out = (float*)d_out;
    const int B = in_sizes[0] / D;
    const int blocks = (B + WPB - 1) / WPB;
    burst_snn_kernel<<<blocks, 1024, 0, stream>>>(x, W1, W2, out, B);
}